// Round 5
// baseline (1658.961 us; speedup 1.0000x reference)
//
#include <hip/hip_runtime.h>
#include <cstdint>
#include <cstddef>

#define NNODE 512
#define MMASK 256
#define ZT 1e-9f
#define NPL 216     // 24 L1 planes + 192 L2 planes
#define NBLK 1024
#define NWAVE 4096

// ---------------- grid barrier (persistent kernel, all blocks resident) -------
// Two-level, monotone phase counters (no resets). bar[] zeroed by k_prep each
// iteration. leaf l at bar[l*16] (64B apart), root at bar[512], flag bar[528].
__device__ __forceinline__ void gbar(unsigned* bar, unsigned phase) {
  __syncthreads();
  if (threadIdx.x == 0) {
    __threadfence();
    unsigned leaf = (unsigned)blockIdx.x & 31u;
    unsigned v = __hip_atomic_fetch_add(&bar[leaf * 16], 1u,
                                        __ATOMIC_ACQ_REL, __HIP_MEMORY_SCOPE_AGENT);
    if (v == phase * (NBLK / 32) - 1) {
      unsigned r = __hip_atomic_fetch_add(&bar[512], 1u,
                                          __ATOMIC_ACQ_REL, __HIP_MEMORY_SCOPE_AGENT);
      if (r == phase * 32 - 1) {
        __hip_atomic_store(&bar[528], phase, __ATOMIC_RELEASE, __HIP_MEMORY_SCOPE_AGENT);
      }
    }
    while (__hip_atomic_load(&bar[528], __ATOMIC_ACQUIRE, __HIP_MEMORY_SCOPE_AGENT) < phase) {
      __builtin_amdgcn_s_sleep(8);
    }
  }
  __syncthreads();
}

// ---------------- prep: ELL build (pad col=0, w=0) + x transpose + bar zero ---
__global__ __launch_bounds__(256) void k_prep(const float* __restrict__ x,
                                              const float* __restrict__ S,
                                              int* __restrict__ sp_col, int* __restrict__ sp_cnt,
                                              int* __restrict__ s_col, float* __restrict__ s_val,
                                              int* __restrict__ s_cnt,
                                              float* __restrict__ xt,
                                              unsigned* __restrict__ bar) {
  int gtid = blockIdx.x * 256 + threadIdx.x;    // grid 128x256 = 32768
  int W = gtid >> 6, lane = threadIdx.x & 63;
  if (gtid < 1024) bar[gtid] = 0u;              // zero barrier words (poisoned by fill)
  // transpose x: (B,N) -> (N,B)
  {
    int n = gtid >> 6, b = gtid & 63;
    xt[gtid] = x[b * NNODE + n];
  }
  // ELL fill, one wave per row
  int m = W;
  int csp = 0, cs = 0;
  unsigned long long lt = (1ull << lane) - 1ull;
  for (int ch = 0; ch < 8; ++ch) {
    int n = ch * 64 + lane;
    float s = S[m * NNODE + n];
    bool ps  = (s != 0.f);
    bool psp = ((fabsf(s) + ((m == n) ? 1.f : 0.f)) > ZT) && !((m >= MMASK) && (n >= MMASK));
    unsigned long long msp = __ballot(psp), ms = __ballot(ps);
    if (psp) { int p = csp + __popcll(msp & lt); if (p < 64) sp_col[(m << 6) + p] = n; }
    if (ps)  { int p = cs  + __popcll(ms  & lt); if (p < 64) { s_col[(m << 6) + p] = n; s_val[(m << 6) + p] = s; } }
    csp += __popcll(msp); cs += __popcll(ms);
  }
  if (lane >= csp) sp_col[(m << 6) + lane] = 0;                       // pad col -> 0
  if (lane >= cs)  { s_col[(m << 6) + lane] = 0; s_val[(m << 6) + lane] = 0.f; }
  if (lane == 0) { sp_cnt[m] = (csp < 64 ? csp : 64); s_cnt[m] = (cs < 64 ? cs : 64); }
}

// ---------------- pack one (plane,row): per-lane vector gather ----------------
__device__ __forceinline__ void pack_one(const float* __restrict__ src,
                                         const int* __restrict__ sp_col,
                                         const int* __restrict__ sp_cnt,
                                         float* __restrict__ wpk,
                                         int pidx, int r, int lane) {
  int cl = sp_col[(r << 6) + lane];
  int cnt = sp_cnt[r];
  float wl = (lane < cnt) ? src[cl] : 0.f;
  wpk[((size_t)pidx << 15) + (r << 6) + lane] = wl;
}

// ---------------- single-stream ELL MAC (LSI u1/u2 path) ----------------
__device__ __forceinline__ float ell_mac_s(const int* __restrict__ cols,
                                           const float* __restrict__ ws,
                                           int cnt,
                                           const float* __restrict__ zin, int lane) {
  float a0 = 0.f, a1 = 0.f, a2 = 0.f, a3 = 0.f;
  for (int base = 0; base < cnt; base += 16) {
#pragma unroll
    for (int i = 0; i < 16; i += 4) {
      int   c0 = cols[base + i    ]; float w0 = ws[base + i    ];
      int   c1 = cols[base + i + 1]; float w1 = ws[base + i + 1];
      int   c2 = cols[base + i + 2]; float w2 = ws[base + i + 2];
      int   c3 = cols[base + i + 3]; float w3 = ws[base + i + 3];
      a0 += w0 * zin[(c0 << 6) + lane];
      a1 += w1 * zin[(c1 << 6) + lane];
      a2 += w2 * zin[(c2 << 6) + lane];
      a3 += w3 * zin[(c3 << 6) + lane];
    }
  }
  return (a0 + a1) + (a2 + a3);
}

// ---------------- the persistent mega-kernel ----------------
__global__ __launch_bounds__(256, 4) void k_mega(
    const float* __restrict__ wEV1, const float* __restrict__ wEV2,
    float* __restrict__ wpk,
    const int* __restrict__ sp_col, const int* __restrict__ sp_cnt,
    const int* __restrict__ s_col, const float* __restrict__ s_val,
    const int* __restrict__ s_cnt,
    const float* __restrict__ xt,
    float* __restrict__ zA1, float* __restrict__ zB1,
    float* __restrict__ u1, float* __restrict__ u2, float* __restrict__ y1,
    const float* __restrict__ wLSI1, const float* __restrict__ b1,
    float* __restrict__ zA2, float* __restrict__ zB2,
    float* __restrict__ v1, float* __restrict__ v2,
    const float* __restrict__ wLSI2, const float* __restrict__ b2,
    float* __restrict__ y2, float* __restrict__ ht,
    const float* __restrict__ W1, const float* __restrict__ bW1,
    const float* __restrict__ W2, const float* __restrict__ bW2,
    float* __restrict__ out, unsigned* __restrict__ bar) {
  int lane = threadIdx.x & 63;
  int gw = __builtin_amdgcn_readfirstlane((int)((blockIdx.x << 2) | (threadIdx.x >> 6)));

  // ---- P1: pack all 24 L1 planes ----
  for (int u = gw; u < 24 * 512; u += NWAVE) {
    int p = u >> 9, r = u & 511;
    pack_one(wEV1 + ((size_t)p << 18) + (r << 9), sp_col, sp_cnt, wpk, p, r, lane);
  }
  gbar(bar, 1);

  // ---- P2: l1s0 MAC (fat-8f shared z=xt) + LSI u1 + pack L2 planes 0..63 ----
  for (int u = gw; u < 1024 + 32768; u += NWAVE) {
    if (u < 512) {
      int r = u;
      const int* cols = sp_col + (r << 6);
      int cnt = sp_cnt[r];
      float acc[8] = {0, 0, 0, 0, 0, 0, 0, 0};
      for (int base = 0; base < cnt; base += 16) {
#pragma unroll
        for (int i = 0; i < 16; i += 4) {
          int c0 = cols[base + i], c1 = cols[base + i + 1];
          int c2 = cols[base + i + 2], c3 = cols[base + i + 3];
          float z0 = xt[(c0 << 6) + lane], z1 = xt[(c1 << 6) + lane];
          float z2 = xt[(c2 << 6) + lane], z3 = xt[(c3 << 6) + lane];
#pragma unroll
          for (int f = 0; f < 8; ++f) {
            const float* wf = wpk + ((size_t)(f * 3) << 15) + (r << 6);
            acc[f] += wf[base + i] * z0 + wf[base + i + 1] * z1
                    + wf[base + i + 2] * z2 + wf[base + i + 3] * z3;
          }
        }
      }
#pragma unroll
      for (int f = 0; f < 8; ++f) zA1[((size_t)f << 15) + (r << 6) + lane] = acc[f];
    } else if (u < 1024) {
      int r = u - 512;
      u1[(r << 6) + lane] =
          ell_mac_s(s_col + (r << 6), s_val + (r << 6), s_cnt[r], xt, lane);
    } else {
      int jj = u - 1024;
      int p2 = jj >> 9, r = jj & 511;
      pack_one(wEV2 + ((size_t)p2 << 18) + (r << 9), sp_col, sp_cnt, wpk, 24 + p2, r, lane);
    }
  }
  gbar(bar, 2);

  // ---- P3: l1s1 MAC (fat-4f) + LSI u2 + pack L2 planes 64..127 ----
  for (int u = gw; u < 1536 + 32768; u += NWAVE) {
    if (u < 1024) {
      int fp = u >> 9, r = u & 511;
      const int* cols = sp_col + (r << 6);
      int cnt = sp_cnt[r];
      float acc[4] = {0, 0, 0, 0};
      for (int base = 0; base < cnt; base += 16) {
#pragma unroll
        for (int i = 0; i < 16; i += 4) {
          int c0 = cols[base + i], c1 = cols[base + i + 1];
          int c2 = cols[base + i + 2], c3 = cols[base + i + 3];
#pragma unroll
          for (int q = 0; q < 4; ++q) {
            int f = fp * 4 + q;
            const float* wf = wpk + ((size_t)(f * 3 + 1) << 15) + (r << 6);
            const float* zq = zA1 + ((size_t)f << 15);
            acc[q] += wf[base + i]     * zq[(c0 << 6) + lane]
                    + wf[base + i + 1] * zq[(c1 << 6) + lane]
                    + wf[base + i + 2] * zq[(c2 << 6) + lane]
                    + wf[base + i + 3] * zq[(c3 << 6) + lane];
          }
        }
      }
#pragma unroll
      for (int q = 0; q < 4; ++q)
        zB1[((size_t)(fp * 4 + q) << 15) + (r << 6) + lane] = acc[q];
    } else if (u < 1536) {
      int r = u - 1024;
      u2[(r << 6) + lane] =
          ell_mac_s(s_col + (r << 6), s_val + (r << 6), s_cnt[r], u1, lane);
    } else {
      int jj = u - 1536;
      int p2 = 64 + (jj >> 9), r = jj & 511;
      pack_one(wEV2 + ((size_t)p2 << 18) + (r << 9), sp_col, sp_cnt, wpk, 24 + p2, r, lane);
    }
  }
  gbar(bar, 3);

  // ---- P4: l1s2 MAC (fat-4f) + epilogue y1 + pack L2 planes 128..191 ----
  for (int u = gw; u < 1024 + 32768; u += NWAVE) {
    if (u < 1024) {
      int fp = u >> 9, r = u & 511;
      const int* cols = sp_col + (r << 6);
      int cnt = sp_cnt[r];
      float acc[4] = {0, 0, 0, 0};
      for (int base = 0; base < cnt; base += 16) {
#pragma unroll
        for (int i = 0; i < 16; i += 4) {
          int c0 = cols[base + i], c1 = cols[base + i + 1];
          int c2 = cols[base + i + 2], c3 = cols[base + i + 3];
#pragma unroll
          for (int q = 0; q < 4; ++q) {
            int f = fp * 4 + q;
            const float* wf = wpk + ((size_t)(f * 3 + 2) << 15) + (r << 6);
            const float* zq = zB1 + ((size_t)f << 15);
            acc[q] += wf[base + i]     * zq[(c0 << 6) + lane]
                    + wf[base + i + 1] * zq[(c1 << 6) + lane]
                    + wf[base + i + 2] * zq[(c2 << 6) + lane]
                    + wf[base + i + 3] * zq[(c3 << 6) + lane];
          }
        }
      }
      int idx = (r << 6) + lane;
      float xv = xt[idx], u1v = u1[idx], u2v = u2[idx];
#pragma unroll
      for (int q = 0; q < 4; ++q) {
        int f = fp * 4 + q;
        size_t fi = ((size_t)f << 15) + idx;
        y1[fi] = zA1[fi] + zB1[fi] + acc[q]
               + wLSI1[f * 3 + 0] * xv + wLSI1[f * 3 + 1] * u1v
               + wLSI1[f * 3 + 2] * u2v + b1[f];
      }
    } else {
      int jj = u - 1024;
      int p2 = 128 + (jj >> 9), r = jj & 511;
      pack_one(wEV2 + ((size_t)p2 << 18) + (r << 9), sp_col, sp_cnt, wpk, 24 + p2, r, lane);
    }
  }
  gbar(bar, 4);

  // ---- P5: l2s0 MAC (fat-8f shared z_g) + LSI v1 (fat-8g) ----
  for (int u = gw; u < 4608; u += NWAVE) {
    if (u < 4096) {
      int g = u >> 9, r = u & 511;
      const int* cols = sp_col + (r << 6);
      int cnt = sp_cnt[r];
      const float* zin = y1 + ((size_t)g << 15);
      float acc[8] = {0, 0, 0, 0, 0, 0, 0, 0};
      for (int base = 0; base < cnt; base += 16) {
#pragma unroll
        for (int i = 0; i < 16; i += 4) {
          int c0 = cols[base + i], c1 = cols[base + i + 1];
          int c2 = cols[base + i + 2], c3 = cols[base + i + 3];
          float z0 = zin[(c0 << 6) + lane], z1 = zin[(c1 << 6) + lane];
          float z2 = zin[(c2 << 6) + lane], z3 = zin[(c3 << 6) + lane];
#pragma unroll
          for (int f = 0; f < 8; ++f) {
            const float* wf = wpk + ((size_t)(24 + (f * 3) * 8 + g) << 15) + (r << 6);
            acc[f] += wf[base + i] * z0 + wf[base + i + 1] * z1
                    + wf[base + i + 2] * z2 + wf[base + i + 3] * z3;
          }
        }
      }
#pragma unroll
      for (int f = 0; f < 8; ++f)
        zA2[((size_t)(f * 8 + g) << 15) + (r << 6) + lane] = acc[f];
    } else {
      int r = u - 4096;
      const int* cols = s_col + (r << 6);
      const float* vals = s_val + (r << 6);
      int cnt = s_cnt[r];
      float acc[8] = {0, 0, 0, 0, 0, 0, 0, 0};
      for (int base = 0; base < cnt; base += 16) {
#pragma unroll
        for (int i = 0; i < 16; i += 2) {
          int c0 = cols[base + i], c1 = cols[base + i + 1];
          float w0 = vals[base + i], w1 = vals[base + i + 1];
#pragma unroll
          for (int g = 0; g < 8; ++g) {
            const float* zg = y1 + ((size_t)g << 15);
            acc[g] += w0 * zg[(c0 << 6) + lane] + w1 * zg[(c1 << 6) + lane];
          }
        }
      }
#pragma unroll
      for (int g = 0; g < 8; ++g)
        v1[((size_t)g << 15) + (r << 6) + lane] = acc[g];
    }
  }
  gbar(bar, 5);

  // ---- P6: l2s1 MAC (fat-8g) + LSI v2 (fat-8g) ----
  for (int u = gw; u < 4608; u += NWAVE) {
    if (u < 4096) {
      int f = u >> 9, r = u & 511;
      const int* cols = sp_col + (r << 6);
      int cnt = sp_cnt[r];
      const float* zb = zA2 + ((size_t)(f * 8) << 15);
      float acc[8] = {0, 0, 0, 0, 0, 0, 0, 0};
      for (int base = 0; base < cnt; base += 16) {
#pragma unroll
        for (int i = 0; i < 16; i += 2) {
          int c0 = cols[base + i], c1 = cols[base + i + 1];
#pragma unroll
          for (int g = 0; g < 8; ++g) {
            const float* wf = wpk + ((size_t)(24 + (f * 3 + 1) * 8 + g) << 15) + (r << 6);
            const float* zg = zb + ((size_t)g << 15);
            acc[g] += wf[base + i]     * zg[(c0 << 6) + lane]
                    + wf[base + i + 1] * zg[(c1 << 6) + lane];
          }
        }
      }
#pragma unroll
      for (int g = 0; g < 8; ++g)
        zB2[((size_t)(f * 8 + g) << 15) + (r << 6) + lane] = acc[g];
    } else {
      int r = u - 4096;
      const int* cols = s_col + (r << 6);
      const float* vals = s_val + (r << 6);
      int cnt = s_cnt[r];
      float acc[8] = {0, 0, 0, 0, 0, 0, 0, 0};
      for (int base = 0; base < cnt; base += 16) {
#pragma unroll
        for (int i = 0; i < 16; i += 2) {
          int c0 = cols[base + i], c1 = cols[base + i + 1];
          float w0 = vals[base + i], w1 = vals[base + i + 1];
#pragma unroll
          for (int g = 0; g < 8; ++g) {
            const float* zg = v1 + ((size_t)g << 15);
            acc[g] += w0 * zg[(c0 << 6) + lane] + w1 * zg[(c1 << 6) + lane];
          }
        }
      }
#pragma unroll
      for (int g = 0; g < 8; ++g)
        v2[((size_t)g << 15) + (r << 6) + lane] = acc[g];
    }
  }
  gbar(bar, 6);

  // ---- P7: l2s2 (fat, 8g inner) + y2 epilogue + ht init + out init ----
  for (int u = gw; u < 4736; u += NWAVE) {
    if (u < 4096) {
      int f = u >> 9, r = u & 511;
      int idx = (r << 6) + lane;
      const int* cols = sp_col + (r << 6);
      int cnt = sp_cnt[r];
      const float* zb = zB2 + ((size_t)(f * 8) << 15);
      float acc8[8] = {0, 0, 0, 0, 0, 0, 0, 0};
      for (int base = 0; base < cnt; base += 16) {
#pragma unroll
        for (int i = 0; i < 16; i += 2) {
          int c0 = cols[base + i], c1 = cols[base + i + 1];
#pragma unroll
          for (int g = 0; g < 8; ++g) {
            const float* wf = wpk + ((size_t)(24 + (f * 3 + 2) * 8 + g) << 15) + (r << 6);
            const float* zg = zb + ((size_t)g << 15);
            acc8[g] += wf[base + i]     * zg[(c0 << 6) + lane]
                     + wf[base + i + 1] * zg[(c1 << 6) + lane];
          }
        }
      }
      float acc = b2[f];
#pragma unroll
      for (int g = 0; g < 8; ++g) {
        int c = f * 8 + g;
        size_t ci = ((size_t)c << 15) + idx;
        size_t gi = ((size_t)g << 15) + idx;
        acc += zA2[ci] + zB2[ci] + acc8[g]
             + wLSI2[f * 24 + g]      * y1[gi]
             + wLSI2[f * 24 + 8 + g]  * v1[gi]
             + wLSI2[f * 24 + 16 + g] * v2[gi];
      }
      y2[((size_t)f << 15) + idx] = acc;
    } else if (u < 4608) {
      int r = u - 4096;
      ht[(r << 6) + lane] = bW1[r];
    } else {
      int j = u - 4608;                       // out init: 128 jobs
      out[(j << 6) + lane] = bW2[((j << 6) + lane) & 127];
    }
  }
  gbar(bar, 7);

  // ---- P8: gemm1, ks=64 splits -> 4096 jobs (1/wave) ----
  for (int u = gw; u < 4096; u += NWAVE) {
    int pg = u >> 6, ks = u & 63;
    const float* wrow = W1 + (size_t)pg * 8 * 4096 + ks * 64;   // uniform -> s_load
    const float* yb = y2 + ((size_t)(ks * 64) << 6);
    float acc[8] = {0, 0, 0, 0, 0, 0, 0, 0};
    for (int q = 0; q < 64; q += 8) {
      float yv[8];
#pragma unroll
      for (int i = 0; i < 8; ++i) yv[i] = yb[((q + i) << 6) + lane];
#pragma unroll
      for (int i = 0; i < 8; ++i) {
#pragma unroll
        for (int p = 0; p < 8; ++p) acc[p] += wrow[(size_t)p * 4096 + q + i] * yv[i];
      }
    }
#pragma unroll
    for (int p = 0; p < 8; ++p) atomicAdd(&ht[((pg * 8 + p) << 6) + lane], acc[p]);
  }
  gbar(bar, 8);

  // ---- P9: gemm2 ----
  for (int u = gw; u < 1024; u += NWAVE) {
    int o = u >> 3, qs = u & 7;
    const float* w2 = W2 + (size_t)o * 512 + qs * 64;            // uniform -> s_load
    const float* hb = ht + ((size_t)(qs * 64) << 6);
    float acc = 0.f;
    for (int q = 0; q < 64; q += 8) {
#pragma unroll
      for (int i = 0; i < 8; ++i) acc += w2[q + i] * hb[((q + i) << 6) + lane];
    }
    atomicAdd(&out[lane * 128 + o], acc);
  }
}

extern "C" void kernel_launch(void* const* d_in, const int* in_sizes, int n_in,
                              void* d_out, int out_size, void* d_ws, size_t ws_size,
                              hipStream_t stream) {
  const float* x     = (const float*)d_in[0];
  const float* S     = (const float*)d_in[1];
  const float* wEV1  = (const float*)d_in[2];
  const float* wLSI1 = (const float*)d_in[3];
  const float* b1    = (const float*)d_in[4];
  const float* wEV2  = (const float*)d_in[5];
  const float* wLSI2 = (const float*)d_in[6];
  const float* b2    = (const float*)d_in[7];
  const float* W1    = (const float*)d_in[8];
  const float* bW1   = (const float*)d_in[9];
  const float* W2    = (const float*)d_in[10];
  const float* bW2   = (const float*)d_in[11];
  float* out = (float*)d_out;

  char* w = (char*)d_ws;
  auto alloc = [&](size_t bytes) { char* p = w; w += (bytes + 255) & ~(size_t)255; return p; };
  unsigned* bar = (unsigned*)alloc(1024 * 4);
  int*   sp_col = (int*)alloc(512 * 64 * 4);
  int*   sp_cnt = (int*)alloc(512 * 4);
  int*   s_col  = (int*)alloc(512 * 64 * 4);
  float* s_val  = (float*)alloc(512 * 64 * 4);
  int*   s_cnt  = (int*)alloc(512 * 4);
  float* wpk    = (float*)alloc((size_t)NPL * 32768 * 4);   // 28.3 MB
  float* xt     = (float*)alloc((size_t)32768 * 4);
  float* u1     = (float*)alloc((size_t)32768 * 4);
  float* u2     = (float*)alloc((size_t)32768 * 4);
  float* zA1    = (float*)alloc((size_t)8 * 32768 * 4);
  float* zB1    = (float*)alloc((size_t)8 * 32768 * 4);
  float* y1     = (float*)alloc((size_t)8 * 32768 * 4);
  float* zA2    = (float*)alloc((size_t)64 * 32768 * 4);    // 8.4 MB
  float* zB2    = (float*)alloc((size_t)64 * 32768 * 4);
  float* v1     = (float*)alloc((size_t)8 * 32768 * 4);
  float* v2     = (float*)alloc((size_t)8 * 32768 * 4);
  float* y2     = (float*)alloc((size_t)8 * 32768 * 4);
  float* ht     = (float*)alloc((size_t)32768 * 4);
  (void)ws_size; (void)in_sizes; (void)n_in; (void)out_size;

  k_prep<<<128, 256, 0, stream>>>(x, S, sp_col, sp_cnt, s_col, s_val, s_cnt, xt, bar);
  k_mega<<<NBLK, 256, 0, stream>>>(wEV1, wEV2, wpk, sp_col, sp_cnt,
                                   s_col, s_val, s_cnt, xt,
                                   zA1, zB1, u1, u2, y1, wLSI1, b1,
                                   zA2, zB2, v1, v2, wLSI2, b2, y2, ht,
                                   W1, bW1, W2, bW2, out, bar);
}

// Round 6
// 420.730 us; speedup vs baseline: 3.9430x; 3.9430x over previous
//
#include <hip/hip_runtime.h>
#include <cstdint>
#include <cstddef>

#define NNODE 512
#define MMASK 256
#define ZT 1e-9f
#define NPL 216     // 24 L1 planes + 192 L2 planes

// ---------------- prep: ELL build (pad col=0, w=0) + x transpose ----------------
__global__ __launch_bounds__(256) void k_prep(const float* __restrict__ x,
                                              const float* __restrict__ S,
                                              int* __restrict__ sp_col, int* __restrict__ sp_cnt,
                                              int* __restrict__ s_col, float* __restrict__ s_val,
                                              int* __restrict__ s_cnt,
                                              float* __restrict__ xt) {
  int gtid = blockIdx.x * 256 + threadIdx.x;    // grid 128x256 = 32768
  int W = gtid >> 6, lane = threadIdx.x & 63;
  // transpose x: (B,N) -> (N,B)
  {
    int n = gtid >> 6, b = gtid & 63;
    xt[gtid] = x[b * NNODE + n];
  }
  // ELL fill, one wave per row
  int m = W;
  int csp = 0, cs = 0;
  unsigned long long lt = (1ull << lane) - 1ull;
  for (int ch = 0; ch < 8; ++ch) {
    int n = ch * 64 + lane;
    float s = S[m * NNODE + n];
    bool ps  = (s != 0.f);
    bool psp = ((fabsf(s) + ((m == n) ? 1.f : 0.f)) > ZT) && !((m >= MMASK) && (n >= MMASK));
    unsigned long long msp = __ballot(psp), ms = __ballot(ps);
    if (psp) { int p = csp + __popcll(msp & lt); if (p < 64) sp_col[(m << 6) + p] = n; }
    if (ps)  { int p = cs  + __popcll(ms  & lt); if (p < 64) { s_col[(m << 6) + p] = n; s_val[(m << 6) + p] = s; } }
    csp += __popcll(msp); cs += __popcll(ms);
  }
  if (lane >= csp) sp_col[(m << 6) + lane] = 0;                       // pad col -> 0
  if (lane >= cs)  { s_col[(m << 6) + lane] = 0; s_val[(m << 6) + lane] = 0.f; }
  if (lane == 0) { sp_cnt[m] = (csp < 64 ? csp : 64); s_cnt[m] = (cs < 64 ? cs : 64); }
}

// ---------------- pack one (plane,row): coalesced stream -> LDS -> gather -----
// Full 2KB row staged with two float4 wave-loads (full BW), gather from LDS.
// Same-wave LDS RAW: compiler inserts lgkmcnt wait. rowslice = rowbuf[wave].
__device__ __forceinline__ void pack_one_lds(const float* __restrict__ src,
                                             float* __restrict__ rowslice,
                                             const int* __restrict__ sp_col,
                                             const int* __restrict__ sp_cnt,
                                             float* __restrict__ wpk,
                                             int pidx, int r, int lane) {
  float4 a = ((const float4*)src)[lane];
  float4 b = ((const float4*)src)[64 + lane];
  ((float4*)rowslice)[lane] = a;
  ((float4*)rowslice)[64 + lane] = b;
  int cl = sp_col[(r << 6) + lane];
  float wl = (lane < sp_cnt[r]) ? rowslice[cl] : 0.f;
  wpk[((size_t)pidx << 15) + (r << 6) + lane] = wl;
}

// ---------------- ELL row MAC, scalarized metadata ----------------
// cols/ws are wave-uniform pointers (derived from readfirstlane'd job index):
// the compiler emits batched s_load for them; only the z-gather is a vector load.
// Pads (col 0, w 0) make full-16 chunks safe.
__device__ __forceinline__ float ell_mac_s(const int* __restrict__ cols,
                                           const float* __restrict__ ws,
                                           int cnt,
                                           const float* __restrict__ zin, int lane) {
  float a0 = 0.f, a1 = 0.f, a2 = 0.f, a3 = 0.f;
  for (int base = 0; base < cnt; base += 16) {
#pragma unroll
    for (int i = 0; i < 16; i += 4) {
      int   c0 = cols[base + i    ]; float w0 = ws[base + i    ];
      int   c1 = cols[base + i + 1]; float w1 = ws[base + i + 1];
      int   c2 = cols[base + i + 2]; float w2 = ws[base + i + 2];
      int   c3 = cols[base + i + 3]; float w3 = ws[base + i + 3];
      a0 += w0 * zin[(c0 << 6) + lane];
      a1 += w1 * zin[(c1 << 6) + lane];
      a2 += w2 * zin[(c2 << 6) + lane];
      a3 += w3 * zin[(c3 << 6) + lane];
    }
  }
  return (a0 + a1) + (a2 + a3);
}

// ---------------- pack L1 planes (24x512 jobs) ----------------
__global__ __launch_bounds__(256) void k_packA(const float* __restrict__ wEV1,
                                               const int* __restrict__ sp_col,
                                               const int* __restrict__ sp_cnt,
                                               float* __restrict__ wpk) {
  __shared__ float rowbuf[4][512];
  int wv = threadIdx.x >> 6, lane = threadIdx.x & 63;
  int W = __builtin_amdgcn_readfirstlane(blockIdx.x * 4 + wv);
  int nwv = gridDim.x * 4;
  for (int u = W; u < 24 * 512; u += nwv) {
    int p = u >> 9, r = u & 511;
    pack_one_lds(wEV1 + ((size_t)p << 18) + (r << 9), rowbuf[wv],
                 sp_col, sp_cnt, wpk, p, r, lane);
  }
}

// ---------------- layer 1 steps (+ hidden L2-plane packing) ----------------
__global__ __launch_bounds__(256) void k_l1s0(const float* __restrict__ wEV2,
    const float* __restrict__ wpk,
    const int* __restrict__ sp_col, const int* __restrict__ sp_cnt,
    const int* __restrict__ s_col, const float* __restrict__ s_val, const int* __restrict__ s_cnt,
    const float* __restrict__ xt, float* __restrict__ zA1, float* __restrict__ u1,
    float* __restrict__ wpk_out) {
  __shared__ float rowbuf[4][512];
  int wv = threadIdx.x >> 6, lane = threadIdx.x & 63;
  int W = __builtin_amdgcn_readfirstlane((blockIdx.x * 256 + (int)threadIdx.x) >> 6);
  int nwv = (gridDim.x << 2);
  for (int u = W; u < 4608 + 32768; u += nwv) {
    if (u < 4096) {
      int f = u >> 9, r = u & 511;
      zA1[((size_t)f << 15) + (r << 6) + lane] =
          ell_mac_s(sp_col + (r << 6), wpk + ((size_t)(f * 3 + 0) << 15) + (r << 6),
                    sp_cnt[r], xt, lane);
    } else if (u < 4608) {
      int r = u - 4096;
      u1[(r << 6) + lane] =
          ell_mac_s(s_col + (r << 6), s_val + (r << 6), s_cnt[r], xt, lane);
    } else {
      int jj = u - 4608;                          // chunk 0: L2 planes 0..63
      int p2 = jj >> 9, r = jj & 511;
      pack_one_lds(wEV2 + ((size_t)p2 << 18) + (r << 9), rowbuf[wv],
                   sp_col, sp_cnt, wpk_out, 24 + p2, r, lane);
    }
  }
}

__global__ __launch_bounds__(256) void k_l1s1(const float* __restrict__ wEV2,
    const float* __restrict__ wpk,
    const int* __restrict__ sp_col, const int* __restrict__ sp_cnt,
    const int* __restrict__ s_col, const float* __restrict__ s_val, const int* __restrict__ s_cnt,
    const float* __restrict__ zA1, const float* __restrict__ u1,
    float* __restrict__ zB1, float* __restrict__ u2,
    float* __restrict__ wpk_out) {
  __shared__ float rowbuf[4][512];
  int wv = threadIdx.x >> 6, lane = threadIdx.x & 63;
  int W = __builtin_amdgcn_readfirstlane((blockIdx.x * 256 + (int)threadIdx.x) >> 6);
  int nwv = (gridDim.x << 2);
  for (int u = W; u < 4608 + 32768; u += nwv) {
    if (u < 4096) {
      int f = u >> 9, r = u & 511;
      zB1[((size_t)f << 15) + (r << 6) + lane] =
          ell_mac_s(sp_col + (r << 6), wpk + ((size_t)(f * 3 + 1) << 15) + (r << 6),
                    sp_cnt[r], zA1 + ((size_t)f << 15), lane);
    } else if (u < 4608) {
      int r = u - 4096;
      u2[(r << 6) + lane] =
          ell_mac_s(s_col + (r << 6), s_val + (r << 6), s_cnt[r], u1, lane);
    } else {
      int jj = u - 4608 + 32768;                  // chunk 1: L2 planes 64..127
      int p2 = jj >> 9, r = jj & 511;
      pack_one_lds(wEV2 + ((size_t)p2 << 18) + (r << 9), rowbuf[wv],
                   sp_col, sp_cnt, wpk_out, 24 + p2, r, lane);
    }
  }
}

__global__ __launch_bounds__(256) void k_l1s2(const float* __restrict__ wEV2,
    const float* __restrict__ wpk,
    const int* __restrict__ sp_col, const int* __restrict__ sp_cnt,
    const float* __restrict__ zA1, const float* __restrict__ zB1,
    const float* __restrict__ xt, const float* __restrict__ u1, const float* __restrict__ u2,
    const float* __restrict__ wLSI1, const float* __restrict__ b1, float* __restrict__ y1,
    float* __restrict__ wpk_out) {
  __shared__ float rowbuf[4][512];
  int wv = threadIdx.x >> 6, lane = threadIdx.x & 63;
  int W = __builtin_amdgcn_readfirstlane((blockIdx.x * 256 + (int)threadIdx.x) >> 6);
  int nwv = (gridDim.x << 2);
  for (int u = W; u < 4096 + 32768; u += nwv) {
    if (u < 4096) {
      int f = u >> 9, r = u & 511;
      float a = ell_mac_s(sp_col + (r << 6), wpk + ((size_t)(f * 3 + 2) << 15) + (r << 6),
                          sp_cnt[r], zB1 + ((size_t)f << 15), lane);
      int idx = (r << 6) + lane;
      size_t fi = ((size_t)f << 15) + idx;
      y1[fi] = zA1[fi] + zB1[fi] + a
             + wLSI1[f * 3 + 0] * xt[idx] + wLSI1[f * 3 + 1] * u1[idx]
             + wLSI1[f * 3 + 2] * u2[idx] + b1[f];
    } else {
      int jj = u - 4096 + 65536;                  // chunk 2: L2 planes 128..191
      int p2 = jj >> 9, r = jj & 511;
      pack_one_lds(wEV2 + ((size_t)p2 << 18) + (r << 9), rowbuf[wv],
                   sp_col, sp_cnt, wpk_out, 24 + p2, r, lane);
    }
  }
}

// ---------------- layer 2 steps ----------------
__global__ __launch_bounds__(256) void k_l2s0(const float* __restrict__ wpk,
    const int* __restrict__ sp_col, const int* __restrict__ sp_cnt,
    const int* __restrict__ s_col, const float* __restrict__ s_val, const int* __restrict__ s_cnt,
    const float* __restrict__ y1, float* __restrict__ zA2, float* __restrict__ v1) {
  int lane = threadIdx.x & 63;
  int W = __builtin_amdgcn_readfirstlane((blockIdx.x * 256 + (int)threadIdx.x) >> 6);
  int nwv = (gridDim.x << 2);
  for (int u = W; u < 36864; u += nwv) {
    if (u < 32768) {
      int c = u >> 9, r = u & 511;
      int f = c >> 3, g = c & 7;
      zA2[((size_t)c << 15) + (r << 6) + lane] =
          ell_mac_s(sp_col + (r << 6),
                    wpk + ((size_t)(24 + (f * 3 + 0) * 8 + g) << 15) + (r << 6),
                    sp_cnt[r], y1 + ((size_t)g << 15), lane);
    } else {
      int t = u - 32768;
      int g = t >> 9, r = t & 511;
      v1[((size_t)g << 15) + (r << 6) + lane] =
          ell_mac_s(s_col + (r << 6), s_val + (r << 6), s_cnt[r],
                    y1 + ((size_t)g << 15), lane);
    }
  }
}

__global__ __launch_bounds__(256) void k_l2s1(const float* __restrict__ wpk,
    const int* __restrict__ sp_col, const int* __restrict__ sp_cnt,
    const int* __restrict__ s_col, const float* __restrict__ s_val, const int* __restrict__ s_cnt,
    const float* __restrict__ zA2, const float* __restrict__ v1,
    float* __restrict__ zB2, float* __restrict__ v2) {
  int lane = threadIdx.x & 63;
  int W = __builtin_amdgcn_readfirstlane((blockIdx.x * 256 + (int)threadIdx.x) >> 6);
  int nwv = (gridDim.x << 2);
  for (int u = W; u < 36864; u += nwv) {
    if (u < 32768) {
      int c = u >> 9, r = u & 511;
      int f = c >> 3, g = c & 7;
      zB2[((size_t)c << 15) + (r << 6) + lane] =
          ell_mac_s(sp_col + (r << 6),
                    wpk + ((size_t)(24 + (f * 3 + 1) * 8 + g) << 15) + (r << 6),
                    sp_cnt[r], zA2 + ((size_t)c << 15), lane);
    } else {
      int t = u - 32768;
      int g = t >> 9, r = t & 511;
      v2[((size_t)g << 15) + (r << 6) + lane] =
          ell_mac_s(s_col + (r << 6), s_val + (r << 6), s_cnt[r],
                    v1 + ((size_t)g << 15), lane);
    }
  }
}

// k2 step: one (f,r) job covers all 8 g -> direct y2 write, no atomics. ht init folded.
__global__ __launch_bounds__(256) void k_l2s2(const float* __restrict__ wpk,
    const int* __restrict__ sp_col, const int* __restrict__ sp_cnt,
    const float* __restrict__ zA2, const float* __restrict__ zB2,
    const float* __restrict__ y1, const float* __restrict__ v1, const float* __restrict__ v2,
    const float* __restrict__ wLSI2, const float* __restrict__ b2,
    const float* __restrict__ bW1, float* __restrict__ y2, float* __restrict__ ht) {
  int gtid = blockIdx.x * 256 + threadIdx.x;
  int lane = threadIdx.x & 63;
  int W = __builtin_amdgcn_readfirstlane(gtid >> 6);
  int nwv = (gridDim.x << 2);
  if (gtid < 32768) ht[gtid] = bW1[gtid >> 6];
  for (int u = W; u < 4096; u += nwv) {
    int f = u >> 9, r = u & 511;
    int idx = (r << 6) + lane;
    const int* cols = sp_col + (r << 6);
    int cnt = sp_cnt[r];
    float acc = b2[f];
#pragma unroll
    for (int g = 0; g < 8; ++g) {
      int c = f * 8 + g;
      float a = ell_mac_s(cols,
                          wpk + ((size_t)(24 + (f * 3 + 2) * 8 + g) << 15) + (r << 6),
                          cnt, zB2 + ((size_t)c << 15), lane);
      size_t ci = ((size_t)c << 15) + idx;
      size_t gi = ((size_t)g << 15) + idx;
      acc += zA2[ci] + zB2[ci] + a
           + wLSI2[f * 24 + g]      * y1[gi]
           + wLSI2[f * 24 + 8 + g]  * v1[gi]
           + wLSI2[f * 24 + 16 + g] * v2[gi];
    }
    y2[((size_t)f << 15) + idx] = acc;
  }
}

// ---------------- readout ----------------
// 8 K-splits: 4x fewer atomics per ht address, jobs = 64 pg x 8 ks = 512.
__global__ __launch_bounds__(256) void k_gemm1(const float* __restrict__ W1,
                                               const float* __restrict__ y2,
                                               const float* __restrict__ bW2,
                                               float* __restrict__ ht,
                                               float* __restrict__ out) {
  int gtid = blockIdx.x * 256 + threadIdx.x;
  int lane = threadIdx.x & 63;
  int W = __builtin_amdgcn_readfirstlane(gtid >> 6);
  int nwv = (gridDim.x << 2);
  if (gtid < 8192) out[gtid] = bW2[gtid & 127];
  for (int u = W; u < 512; u += nwv) {
    int pg = u >> 3, ks = u & 7;
    const float* wrow = W1 + (size_t)pg * 8 * 4096 + ks * 512;   // uniform -> s_load
    const float* yb = y2 + ((size_t)(ks * 512) << 6);
    float acc[8] = {0, 0, 0, 0, 0, 0, 0, 0};
    for (int q = 0; q < 512; q += 8) {
      float yv[8];
#pragma unroll
      for (int i = 0; i < 8; ++i) yv[i] = yb[((q + i) << 6) + lane];
#pragma unroll
      for (int i = 0; i < 8; ++i) {
#pragma unroll
        for (int p = 0; p < 8; ++p) acc[p] += wrow[(size_t)p * 4096 + q + i] * yv[i];
      }
    }
#pragma unroll
    for (int p = 0; p < 8; ++p) atomicAdd(&ht[((pg * 8 + p) << 6) + lane], acc[p]);
  }
}

__global__ __launch_bounds__(256) void k_gemm2(const float* __restrict__ W2,
                                               const float* __restrict__ ht,
                                               float* __restrict__ out) {
  int lane = threadIdx.x & 63;
  int W = __builtin_amdgcn_readfirstlane((blockIdx.x * 256 + (int)threadIdx.x) >> 6);
  int nwv = (gridDim.x << 2);
  for (int u = W; u < 1024; u += nwv) {
    int o = u >> 3, qs = u & 7;
    const float* w2 = W2 + (size_t)o * 512 + qs * 64;            // uniform -> s_load
    const float* hb = ht + ((size_t)(qs * 64) << 6);
    float acc = 0.f;
    for (int q = 0; q < 64; q += 8) {
#pragma unroll
      for (int i = 0; i < 8; ++i) acc += w2[q + i] * hb[((q + i) << 6) + lane];
    }
    atomicAdd(&out[lane * 128 + o], acc);
  }
}

extern "C" void kernel_launch(void* const* d_in, const int* in_sizes, int n_in,
                              void* d_out, int out_size, void* d_ws, size_t ws_size,
                              hipStream_t stream) {
  const float* x     = (const float*)d_in[0];
  const float* S     = (const float*)d_in[1];
  const float* wEV1  = (const float*)d_in[2];
  const float* wLSI1 = (const float*)d_in[3];
  const float* b1    = (const float*)d_in[4];
  const float* wEV2  = (const float*)d_in[5];
  const float* wLSI2 = (const float*)d_in[6];
  const float* b2    = (const float*)d_in[7];
  const float* W1    = (const float*)d_in[8];
  const float* bW1   = (const float*)d_in[9];
  const float* W2    = (const float*)d_in[10];
  const float* bW2   = (const float*)d_in[11];
  float* out = (float*)d_out;

  char* w = (char*)d_ws;
  auto alloc = [&](size_t bytes) { char* p = w; w += (bytes + 255) & ~(size_t)255; return p; };
  int*   sp_col = (int*)alloc(512 * 64 * 4);
  int*   sp_cnt = (int*)alloc(512 * 4);
  int*   s_col  = (int*)alloc(512 * 64 * 4);
  float* s_val  = (float*)alloc(512 * 64 * 4);
  int*   s_cnt  = (int*)alloc(512 * 4);
  float* wpk    = (float*)alloc((size_t)NPL * 32768 * 4);   // 28.3 MB
  float* xt     = (float*)alloc((size_t)32768 * 4);
  float* u1     = (float*)alloc((size_t)32768 * 4);
  float* u2     = (float*)alloc((size_t)32768 * 4);
  float* zA1    = (float*)alloc((size_t)8 * 32768 * 4);
  float* zB1    = (float*)alloc((size_t)8 * 32768 * 4);
  float* y1     = (float*)alloc((size_t)8 * 32768 * 4);
  float* zA2    = (float*)alloc((size_t)64 * 32768 * 4);    // 8.4 MB
  float* zB2    = (float*)alloc((size_t)64 * 32768 * 4);
  float* v1     = (float*)alloc((size_t)8 * 32768 * 4);
  float* v2     = (float*)alloc((size_t)8 * 32768 * 4);
  float* y2     = (float*)alloc((size_t)8 * 32768 * 4);
  float* ht     = (float*)alloc((size_t)32768 * 4);
  (void)ws_size; (void)in_sizes; (void)n_in; (void)out_size;

  k_prep<<<128, 256, 0, stream>>>(x, S, sp_col, sp_cnt, s_col, s_val, s_cnt, xt);
  k_packA<<<3072, 256, 0, stream>>>(wEV1, sp_col, sp_cnt, wpk);
  k_l1s0<<<9344, 256, 0, stream>>>(wEV2, wpk, sp_col, sp_cnt, s_col, s_val, s_cnt, xt, zA1, u1, wpk);
  k_l1s1<<<9344, 256, 0, stream>>>(wEV2, wpk, sp_col, sp_cnt, s_col, s_val, s_cnt, zA1, u1, zB1, u2, wpk);
  k_l1s2<<<9216, 256, 0, stream>>>(wEV2, wpk, sp_col, sp_cnt, zA1, zB1, xt, u1, u2, wLSI1, b1, y1, wpk);
  k_l2s0<<<9216, 256, 0, stream>>>(wpk, sp_col, sp_cnt, s_col, s_val, s_cnt, y1, zA2, v1);
  k_l2s1<<<9216, 256, 0, stream>>>(wpk, sp_col, sp_cnt, s_col, s_val, s_cnt, zA2, v1, zB2, v2);
  k_l2s2<<<1024, 256, 0, stream>>>(wpk, sp_col, sp_cnt, zA2, zB2, y1, v1, v2, wLSI2, b2, bW1, y2, ht);
  k_gemm1<<<128, 256, 0, stream>>>(W1, y2, bW2, ht, out);
  k_gemm2<<<64, 256, 0, stream>>>(W2, ht, out);
}

// Round 7
// 396.527 us; speedup vs baseline: 4.1837x; 1.0610x over previous
//
#include <hip/hip_runtime.h>
#include <cstdint>
#include <cstddef>

#define NNODE 512
#define MMASK 256
#define ZT 1e-9f

__device__ __forceinline__ float rdl_f(float v, int l) {
  return __uint_as_float(__builtin_amdgcn_readlane(__float_as_uint(v), l));
}

// ---------------- prep: ELL build (pad col=0, w=0) + x transpose ----------------
__global__ __launch_bounds__(256) void k_prep(const float* __restrict__ x,
                                              const float* __restrict__ S,
                                              int* __restrict__ sp_col, int* __restrict__ sp_cnt,
                                              int* __restrict__ s_col, float* __restrict__ s_val,
                                              int* __restrict__ s_cnt,
                                              float* __restrict__ xt) {
  int gtid = blockIdx.x * 256 + threadIdx.x;    // grid 128x256 = 32768
  int W = gtid >> 6, lane = threadIdx.x & 63;
  // transpose x: (B,N) -> (N,B)
  {
    int n = gtid >> 6, b = gtid & 63;
    xt[gtid] = x[b * NNODE + n];
  }
  // ELL fill, one wave per row
  int m = W;
  int csp = 0, cs = 0;
  unsigned long long lt = (1ull << lane) - 1ull;
  for (int ch = 0; ch < 8; ++ch) {
    int n = ch * 64 + lane;
    float s = S[m * NNODE + n];
    bool ps  = (s != 0.f);
    bool psp = ((fabsf(s) + ((m == n) ? 1.f : 0.f)) > ZT) && !((m >= MMASK) && (n >= MMASK));
    unsigned long long msp = __ballot(psp), ms = __ballot(ps);
    if (psp) { int p = csp + __popcll(msp & lt); if (p < 64) sp_col[(m << 6) + p] = n; }
    if (ps)  { int p = cs  + __popcll(ms  & lt); if (p < 64) { s_col[(m << 6) + p] = n; s_val[(m << 6) + p] = s; } }
    csp += __popcll(msp); cs += __popcll(ms);
  }
  if (lane >= csp) sp_col[(m << 6) + lane] = 0;                       // pad col -> 0
  if (lane >= cs)  { s_col[(m << 6) + lane] = 0; s_val[(m << 6) + lane] = 0.f; }
  if (lane == 0) { sp_cnt[m] = (csp < 64 ? csp : 64); s_cnt[m] = (cs < 64 ? cs : 64); }
}

// ---------------- ELL row MAC, register-resident weights -----------------------
// clv: per-lane col (lane = ELL slot). wgv: per-lane gathered weight (0 for pads).
// base+i is wave-uniform -> readlane puts col/weight into SGPRs; z-gather is the
// only vector load (256B coalesced over batch). No LDS, no SMEM weight loads.
__device__ __forceinline__ float ell_mac_rl(int clv, float wgv, int cnt,
                                            const float* __restrict__ zin, int lane) {
  float a0 = 0.f, a1 = 0.f, a2 = 0.f, a3 = 0.f;
  for (int base = 0; base < cnt; base += 16) {
#pragma unroll
    for (int i = 0; i < 16; i += 4) {
      int   c0 = __builtin_amdgcn_readlane(clv, base + i);
      int   c1 = __builtin_amdgcn_readlane(clv, base + i + 1);
      int   c2 = __builtin_amdgcn_readlane(clv, base + i + 2);
      int   c3 = __builtin_amdgcn_readlane(clv, base + i + 3);
      float w0 = rdl_f(wgv, base + i);
      float w1 = rdl_f(wgv, base + i + 1);
      float w2 = rdl_f(wgv, base + i + 2);
      float w3 = rdl_f(wgv, base + i + 3);
      a0 += w0 * zin[(c0 << 6) + lane];
      a1 += w1 * zin[(c1 << 6) + lane];
      a2 += w2 * zin[(c2 << 6) + lane];
      a3 += w3 * zin[(c3 << 6) + lane];
    }
  }
  return (a0 + a1) + (a2 + a3);
}

// ---------------- single-stream ELL MAC, packed weights (LSI path) -------------
__device__ __forceinline__ float ell_mac_s(const int* __restrict__ cols,
                                           const float* __restrict__ ws,
                                           int cnt,
                                           const float* __restrict__ zin, int lane) {
  float a0 = 0.f, a1 = 0.f, a2 = 0.f, a3 = 0.f;
  for (int base = 0; base < cnt; base += 16) {
#pragma unroll
    for (int i = 0; i < 16; i += 4) {
      int   c0 = cols[base + i    ]; float w0 = ws[base + i    ];
      int   c1 = cols[base + i + 1]; float w1 = ws[base + i + 1];
      int   c2 = cols[base + i + 2]; float w2 = ws[base + i + 2];
      int   c3 = cols[base + i + 3]; float w3 = ws[base + i + 3];
      a0 += w0 * zin[(c0 << 6) + lane];
      a1 += w1 * zin[(c1 << 6) + lane];
      a2 += w2 * zin[(c2 << 6) + lane];
      a3 += w3 * zin[(c3 << 6) + lane];
    }
  }
  return (a0 + a1) + (a2 + a3);
}

// ---------------- layer 1 steps ----------------
__global__ __launch_bounds__(256) void k_l1s0(const float* __restrict__ wEV1,
    const int* __restrict__ sp_col, const int* __restrict__ sp_cnt,
    const int* __restrict__ s_col, const float* __restrict__ s_val, const int* __restrict__ s_cnt,
    const float* __restrict__ xt, float* __restrict__ zA1, float* __restrict__ u1) {
  int lane = threadIdx.x & 63;
  int W = __builtin_amdgcn_readfirstlane((blockIdx.x * 256 + (int)threadIdx.x) >> 6);
  int nwv = (gridDim.x << 2);
  for (int u = W; u < 4608; u += nwv) {
    if (u < 4096) {
      int f = u >> 9, r = u & 511;
      int clv = sp_col[(r << 6) + lane];
      int cnt = sp_cnt[r];
      const float* wrow = wEV1 + ((size_t)(f * 3 + 0) << 18) + ((size_t)r << 9);
      float wgv = (lane < cnt) ? wrow[clv] : 0.f;
      zA1[((size_t)f << 15) + (r << 6) + lane] = ell_mac_rl(clv, wgv, cnt, xt, lane);
    } else {
      int r = u - 4096;
      u1[(r << 6) + lane] =
          ell_mac_s(s_col + (r << 6), s_val + (r << 6), s_cnt[r], xt, lane);
    }
  }
}

__global__ __launch_bounds__(256) void k_l1s1(const float* __restrict__ wEV1,
    const int* __restrict__ sp_col, const int* __restrict__ sp_cnt,
    const int* __restrict__ s_col, const float* __restrict__ s_val, const int* __restrict__ s_cnt,
    const float* __restrict__ zA1, const float* __restrict__ u1,
    float* __restrict__ zB1, float* __restrict__ u2) {
  int lane = threadIdx.x & 63;
  int W = __builtin_amdgcn_readfirstlane((blockIdx.x * 256 + (int)threadIdx.x) >> 6);
  int nwv = (gridDim.x << 2);
  for (int u = W; u < 4608; u += nwv) {
    if (u < 4096) {
      int f = u >> 9, r = u & 511;
      int clv = sp_col[(r << 6) + lane];
      int cnt = sp_cnt[r];
      const float* wrow = wEV1 + ((size_t)(f * 3 + 1) << 18) + ((size_t)r << 9);
      float wgv = (lane < cnt) ? wrow[clv] : 0.f;
      zB1[((size_t)f << 15) + (r << 6) + lane] =
          ell_mac_rl(clv, wgv, cnt, zA1 + ((size_t)f << 15), lane);
    } else {
      int r = u - 4096;
      u2[(r << 6) + lane] =
          ell_mac_s(s_col + (r << 6), s_val + (r << 6), s_cnt[r], u1, lane);
    }
  }
}

__global__ __launch_bounds__(256) void k_l1s2(const float* __restrict__ wEV1,
    const int* __restrict__ sp_col, const int* __restrict__ sp_cnt,
    const float* __restrict__ zA1, const float* __restrict__ zB1,
    const float* __restrict__ xt, const float* __restrict__ u1, const float* __restrict__ u2,
    const float* __restrict__ wLSI1, const float* __restrict__ b1, float* __restrict__ y1) {
  int lane = threadIdx.x & 63;
  int W = __builtin_amdgcn_readfirstlane((blockIdx.x * 256 + (int)threadIdx.x) >> 6);
  int nwv = (gridDim.x << 2);
  for (int u = W; u < 4096; u += nwv) {
    int f = u >> 9, r = u & 511;
    int clv = sp_col[(r << 6) + lane];
    int cnt = sp_cnt[r];
    const float* wrow = wEV1 + ((size_t)(f * 3 + 2) << 18) + ((size_t)r << 9);
    float wgv = (lane < cnt) ? wrow[clv] : 0.f;
    float a = ell_mac_rl(clv, wgv, cnt, zB1 + ((size_t)f << 15), lane);
    int idx = (r << 6) + lane;
    size_t fi = ((size_t)f << 15) + idx;
    y1[fi] = zA1[fi] + zB1[fi] + a
           + wLSI1[f * 3 + 0] * xt[idx] + wLSI1[f * 3 + 1] * u1[idx]
           + wLSI1[f * 3 + 2] * u2[idx] + b1[f];
  }
}

// ---------------- layer 2 steps ----------------
__global__ __launch_bounds__(256) void k_l2s0(const float* __restrict__ wEV2,
    const int* __restrict__ sp_col, const int* __restrict__ sp_cnt,
    const int* __restrict__ s_col, const float* __restrict__ s_val, const int* __restrict__ s_cnt,
    const float* __restrict__ y1, float* __restrict__ zA2, float* __restrict__ v1) {
  int lane = threadIdx.x & 63;
  int W = __builtin_amdgcn_readfirstlane((blockIdx.x * 256 + (int)threadIdx.x) >> 6);
  int nwv = (gridDim.x << 2);
  for (int u = W; u < 36864; u += nwv) {
    if (u < 32768) {
      int c = u >> 9, r = u & 511;
      int f = c >> 3, g = c & 7;
      int clv = sp_col[(r << 6) + lane];
      int cnt = sp_cnt[r];
      const float* wrow = wEV2 + ((size_t)((f * 3 + 0) * 8 + g) << 18) + ((size_t)r << 9);
      float wgv = (lane < cnt) ? wrow[clv] : 0.f;
      zA2[((size_t)c << 15) + (r << 6) + lane] =
          ell_mac_rl(clv, wgv, cnt, y1 + ((size_t)g << 15), lane);
    } else {
      int t = u - 32768;
      int g = t >> 9, r = t & 511;
      v1[((size_t)g << 15) + (r << 6) + lane] =
          ell_mac_s(s_col + (r << 6), s_val + (r << 6), s_cnt[r],
                    y1 + ((size_t)g << 15), lane);
    }
  }
}

__global__ __launch_bounds__(256) void k_l2s1(const float* __restrict__ wEV2,
    const int* __restrict__ sp_col, const int* __restrict__ sp_cnt,
    const int* __restrict__ s_col, const float* __restrict__ s_val, const int* __restrict__ s_cnt,
    const float* __restrict__ zA2, const float* __restrict__ v1,
    float* __restrict__ zB2, float* __restrict__ v2) {
  int lane = threadIdx.x & 63;
  int W = __builtin_amdgcn_readfirstlane((blockIdx.x * 256 + (int)threadIdx.x) >> 6);
  int nwv = (gridDim.x << 2);
  for (int u = W; u < 36864; u += nwv) {
    if (u < 32768) {
      int c = u >> 9, r = u & 511;
      int f = c >> 3, g = c & 7;
      int clv = sp_col[(r << 6) + lane];
      int cnt = sp_cnt[r];
      const float* wrow = wEV2 + ((size_t)((f * 3 + 1) * 8 + g) << 18) + ((size_t)r << 9);
      float wgv = (lane < cnt) ? wrow[clv] : 0.f;
      zB2[((size_t)c << 15) + (r << 6) + lane] =
          ell_mac_rl(clv, wgv, cnt, zA2 + ((size_t)c << 15), lane);
    } else {
      int t = u - 32768;
      int g = t >> 9, r = t & 511;
      v2[((size_t)g << 15) + (r << 6) + lane] =
          ell_mac_s(s_col + (r << 6), s_val + (r << 6), s_cnt[r],
                    v1 + ((size_t)g << 15), lane);
    }
  }
}

// k2 step: one (f,r) job covers all 8 g -> direct y2 write, no atomics. ht init folded.
__global__ __launch_bounds__(256) void k_l2s2(const float* __restrict__ wEV2,
    const int* __restrict__ sp_col, const int* __restrict__ sp_cnt,
    const float* __restrict__ zA2, const float* __restrict__ zB2,
    const float* __restrict__ y1, const float* __restrict__ v1, const float* __restrict__ v2,
    const float* __restrict__ wLSI2, const float* __restrict__ b2,
    const float* __restrict__ bW1, float* __restrict__ y2, float* __restrict__ ht) {
  int gtid = blockIdx.x * 256 + threadIdx.x;
  int lane = threadIdx.x & 63;
  int W = __builtin_amdgcn_readfirstlane(gtid >> 6);
  int nwv = (gridDim.x << 2);
  if (gtid < 32768) ht[gtid] = bW1[gtid >> 6];
  for (int u = W; u < 4096; u += nwv) {
    int f = u >> 9, r = u & 511;
    int idx = (r << 6) + lane;
    int clv = sp_col[(r << 6) + lane];
    int cnt = sp_cnt[r];
    // issue all 8 weight gathers first (memory-level parallelism)
    float wg[8];
#pragma unroll
    for (int g = 0; g < 8; ++g) {
      const float* wrow = wEV2 + ((size_t)((f * 3 + 2) * 8 + g) << 18) + ((size_t)r << 9);
      wg[g] = (lane < cnt) ? wrow[clv] : 0.f;
    }
    float acc = b2[f];
#pragma unroll
    for (int g = 0; g < 8; ++g) {
      int c = f * 8 + g;
      float a = ell_mac_rl(clv, wg[g], cnt, zB2 + ((size_t)c << 15), lane);
      size_t ci = ((size_t)c << 15) + idx;
      size_t gi = ((size_t)g << 15) + idx;
      acc += zA2[ci] + zB2[ci] + a
           + wLSI2[f * 24 + g]      * y1[gi]
           + wLSI2[f * 24 + 8 + g]  * v1[gi]
           + wLSI2[f * 24 + 16 + g] * v2[gi];
    }
    y2[((size_t)f << 15) + idx] = acc;
  }
}

// ---------------- readout ----------------
// 8 K-splits: jobs = 64 pg x 8 ks = 512.
__global__ __launch_bounds__(256) void k_gemm1(const float* __restrict__ W1,
                                               const float* __restrict__ y2,
                                               const float* __restrict__ bW2,
                                               float* __restrict__ ht,
                                               float* __restrict__ out) {
  int gtid = blockIdx.x * 256 + threadIdx.x;
  int lane = threadIdx.x & 63;
  int W = __builtin_amdgcn_readfirstlane(gtid >> 6);
  int nwv = (gridDim.x << 2);
  if (gtid < 8192) out[gtid] = bW2[gtid & 127];
  for (int u = W; u < 512; u += nwv) {
    int pg = u >> 3, ks = u & 7;
    const float* wrow = W1 + (size_t)pg * 8 * 4096 + ks * 512;   // uniform -> s_load
    const float* yb = y2 + ((size_t)(ks * 512) << 6);
    float acc[8] = {0, 0, 0, 0, 0, 0, 0, 0};
    for (int q = 0; q < 512; q += 8) {
      float yv[8];
#pragma unroll
      for (int i = 0; i < 8; ++i) yv[i] = yb[((q + i) << 6) + lane];
#pragma unroll
      for (int i = 0; i < 8; ++i) {
#pragma unroll
        for (int p = 0; p < 8; ++p) acc[p] += wrow[(size_t)p * 4096 + q + i] * yv[i];
      }
    }
#pragma unroll
    for (int p = 0; p < 8; ++p) atomicAdd(&ht[((pg * 8 + p) << 6) + lane], acc[p]);
  }
}

__global__ __launch_bounds__(256) void k_gemm2(const float* __restrict__ W2,
                                               const float* __restrict__ ht,
                                               float* __restrict__ out) {
  int lane = threadIdx.x & 63;
  int W = __builtin_amdgcn_readfirstlane((blockIdx.x * 256 + (int)threadIdx.x) >> 6);
  int nwv = (gridDim.x << 2);
  for (int u = W; u < 1024; u += nwv) {
    int o = u >> 3, qs = u & 7;
    const float* w2 = W2 + (size_t)o * 512 + qs * 64;            // uniform -> s_load
    const float* hb = ht + ((size_t)(qs * 64) << 6);
    float acc = 0.f;
    for (int q = 0; q < 64; q += 8) {
#pragma unroll
      for (int i = 0; i < 8; ++i) acc += w2[q + i] * hb[((q + i) << 6) + lane];
    }
    atomicAdd(&out[lane * 128 + o], acc);
  }
}

extern "C" void kernel_launch(void* const* d_in, const int* in_sizes, int n_in,
                              void* d_out, int out_size, void* d_ws, size_t ws_size,
                              hipStream_t stream) {
  const float* x     = (const float*)d_in[0];
  const float* S     = (const float*)d_in[1];
  const float* wEV1  = (const float*)d_in[2];
  const float* wLSI1 = (const float*)d_in[3];
  const float* b1    = (const float*)d_in[4];
  const float* wEV2  = (const float*)d_in[5];
  const float* wLSI2 = (const float*)d_in[6];
  const float* b2    = (const float*)d_in[7];
  const float* W1    = (const float*)d_in[8];
  const float* bW1   = (const float*)d_in[9];
  const float* W2    = (const float*)d_in[10];
  const float* bW2   = (const float*)d_in[11];
  float* out = (float*)d_out;

  char* w = (char*)d_ws;
  auto alloc = [&](size_t bytes) { char* p = w; w += (bytes + 255) & ~(size_t)255; return p; };
  int*   sp_col = (int*)alloc(512 * 64 * 4);
  int*   sp_cnt = (int*)alloc(512 * 4);
  int*   s_col  = (int*)alloc(512 * 64 * 4);
  float* s_val  = (float*)alloc(512 * 64 * 4);
  int*   s_cnt  = (int*)alloc(512 * 4);
  float* xt     = (float*)alloc((size_t)32768 * 4);
  float* u1     = (float*)alloc((size_t)32768 * 4);
  float* u2     = (float*)alloc((size_t)32768 * 4);
  float* zA1    = (float*)alloc((size_t)8 * 32768 * 4);
  float* zB1    = (float*)alloc((size_t)8 * 32768 * 4);
  float* y1     = (float*)alloc((size_t)8 * 32768 * 4);
  float* zA2    = (float*)alloc((size_t)64 * 32768 * 4);    // 8.4 MB
  float* zB2    = (float*)alloc((size_t)64 * 32768 * 4);
  float* v1     = (float*)alloc((size_t)8 * 32768 * 4);
  float* v2     = (float*)alloc((size_t)8 * 32768 * 4);
  float* y2     = (float*)alloc((size_t)8 * 32768 * 4);
  float* ht     = (float*)alloc((size_t)32768 * 4);
  (void)ws_size; (void)in_sizes; (void)n_in; (void)out_size;

  k_prep<<<128, 256, 0, stream>>>(x, S, sp_col, sp_cnt, s_col, s_val, s_cnt, xt);
  k_l1s0<<<1152, 256, 0, stream>>>(wEV1, sp_col, sp_cnt, s_col, s_val, s_cnt, xt, zA1, u1);
  k_l1s1<<<1152, 256, 0, stream>>>(wEV1, sp_col, sp_cnt, s_col, s_val, s_cnt, zA1, u1, zB1, u2);
  k_l1s2<<<1024, 256, 0, stream>>>(wEV1, sp_col, sp_cnt, zA1, zB1, xt, u1, u2, wLSI1, b1, y1);
  k_l2s0<<<9216, 256, 0, stream>>>(wEV2, sp_col, sp_cnt, s_col, s_val, s_cnt, y1, zA2, v1);
  k_l2s1<<<9216, 256, 0, stream>>>(wEV2, sp_col, sp_cnt, s_col, s_val, s_cnt, zA2, v1, zB2, v2);
  k_l2s2<<<1024, 256, 0, stream>>>(wEV2, sp_col, sp_cnt, zA2, zB2, y1, v1, v2, wLSI2, b2, bW1, y2, ht);
  k_gemm1<<<128, 256, 0, stream>>>(W1, y2, bW2, ht, out);
  k_gemm2<<<64, 256, 0, stream>>>(W2, ht, out);
}